// Round 1
// baseline (168.284 us; speedup 1.0000x reference)
//
#include <hip/hip_runtime.h>

#define NATOMS 131072
#define CSTF 1.676543f

__device__ __forceinline__ float silu_n(float y) {
    // CST * y * sigmoid(y)
    float t = __expf(-y);
    float sg = __builtin_amdgcn_rcpf(1.0f + t);
    return CSTF * y * sg;
}

// Phase 1: per-atom s2 = silu(silu(x0 @ W0c * .125) @ W1c * .125),
// accumulated per (batch, channel) into per-block LDS tables, flushed to ws.
// One wave processes one atom at a time; lane = output channel o (0..63).
// Weight columns W[:, lane] live in VGPRs. x[m] comes in as wave-uniform
// scalar loads; s1[m] is broadcast with v_readlane.
__global__ __launch_bounds__(512, 1) void phase1_kernel(
    const float* __restrict__ x, const int* __restrict__ bidx,
    const float* __restrict__ W0, const float* __restrict__ W1,
    float* __restrict__ ws, int APB, int chunk)
{
    __shared__ float acc[256 * 64];  // 64 KB: half of the 512-batch table
    const int tid  = threadIdx.x;
    const int lane = tid & 63;
    const int wave = tid >> 6;
    const int blk  = blockIdx.x;

    // Preload weight columns: W0_0[m, lane], W1_0[m, lane]  (W rows are 256 wide)
    float w0c[64], w1c[64];
#pragma unroll
    for (int m = 0; m < 64; ++m) {
        w0c[m] = W0[m * 256 + lane];
        w1c[m] = W1[m * 256 + lane];
    }

    const int ablock_end = min(NATOMS, (blk + 1) * APB);
    const int base = blk * APB + wave * chunk;

    for (int pass = 0; pass < 2; ++pass) {
        for (int i = tid; i < 256 * 64; i += 512) acc[i] = 0.0f;
        __syncthreads();

        const int blo = pass * 256, bhi = blo + 256;
        for (int i = 0; i < chunk; ++i) {
            const int a = base + i;
            if (a >= ablock_end) break;
            const int b = __builtin_amdgcn_readfirstlane(bidx[a]);
            if (b < blo || b >= bhi) continue;

            const float* xr = x + (size_t)__builtin_amdgcn_readfirstlane(a) * 1024;

            // stage 1: y[lane] = sum_m x[m] * W0[m,lane]
            float y0 = 0.f, y1 = 0.f, y2 = 0.f, y3 = 0.f;
#pragma unroll
            for (int m = 0; m < 64; m += 4) {
                y0 = fmaf(xr[m + 0], w0c[m + 0], y0);
                y1 = fmaf(xr[m + 1], w0c[m + 1], y1);
                y2 = fmaf(xr[m + 2], w0c[m + 2], y2);
                y3 = fmaf(xr[m + 3], w0c[m + 3], y3);
            }
            const float s1 = silu_n(((y0 + y1) + (y2 + y3)) * 0.125f);

            // stage 2: z[lane] = sum_m s1[m] * W1[m,lane]; s1[m] lives in lane m
            float z0 = 0.f, z1 = 0.f, z2 = 0.f, z3 = 0.f;
#pragma unroll
            for (int m = 0; m < 64; m += 4) {
                const float b0 = __uint_as_float(__builtin_amdgcn_readlane(__float_as_uint(s1), m + 0));
                const float b1 = __uint_as_float(__builtin_amdgcn_readlane(__float_as_uint(s1), m + 1));
                const float b2 = __uint_as_float(__builtin_amdgcn_readlane(__float_as_uint(s1), m + 2));
                const float b3 = __uint_as_float(__builtin_amdgcn_readlane(__float_as_uint(s1), m + 3));
                z0 = fmaf(b0, w1c[m + 0], z0);
                z1 = fmaf(b1, w1c[m + 1], z1);
                z2 = fmaf(b2, w1c[m + 2], z2);
                z3 = fmaf(b3, w1c[m + 3], z3);
            }
            const float s2 = silu_n(((z0 + z1) + (z2 + z3)) * 0.125f);

            atomicAdd(&acc[(b - blo) * 64 + lane], s2);  // ds_add_f32, conflict-free
        }
        __syncthreads();

        // flush this half-table to the block's ws slice (plain coalesced stores)
        float* dst = ws + (size_t)blk * 32768 + (size_t)pass * 16384;
        for (int i = tid; i < 16384; i += 512) dst[i] = acc[i];
        __syncthreads();
    }
}

// Phase 2: S[b, o] = sum over NB block tables; out[b, f] = 0.125 * S[b,:] @ W_out
__global__ __launch_bounds__(128) void phase2_kernel(
    const float* __restrict__ ws, const float* __restrict__ Wout,
    float* __restrict__ out, int NB)
{
    __shared__ float sp[128];
    const int b = blockIdx.x;
    const int t = threadIdx.x;
    const int o = t & 63;
    const int half = t >> 6;

    float s = 0.f;
    for (int blk = half; blk < NB; blk += 2)
        s += ws[(size_t)blk * 32768 + b * 64 + o];
    sp[t] = s;
    __syncthreads();

    float r = 0.f;
#pragma unroll
    for (int o2 = 0; o2 < 64; ++o2) {
        const float S = sp[o2] + sp[o2 + 64];
        r = fmaf(S, Wout[o2 * 128 + t], r);
    }
    out[b * 128 + t] = 0.125f * r;
}

extern "C" void kernel_launch(void* const* d_in, const int* in_sizes, int n_in,
                              void* d_out, int out_size, void* d_ws, size_t ws_size,
                              hipStream_t stream)
{
    const float* x    = (const float*)d_in[0];
    const int*   bidx = (const int*)d_in[1];
    const float* W0   = (const float*)d_in[3];   // W0_0 (64,256)
    const float* W1   = (const float*)d_in[7];   // W1_0 (64,256)
    const float* Wout = (const float*)d_in[11];  // W_out (64,128)
    float* ws = (float*)d_ws;
    float* out = (float*)d_out;

    int NB = (int)(ws_size / (32768u * 4u));
    if (NB > 256) NB = 256;
    if (NB < 1)   NB = 1;
    const int APB   = (NATOMS + NB - 1) / NB;   // atoms per block
    const int chunk = (APB + 7) / 8;            // atoms per wave (8 waves/block)

    hipLaunchKernelGGL(phase1_kernel, dim3(NB), dim3(512), 0, stream,
                       x, bidx, W0, W1, ws, APB, chunk);
    hipLaunchKernelGGL(phase2_kernel, dim3(512), dim3(128), 0, stream,
                       ws, Wout, out, NB);
}

// Round 2
// 85.499 us; speedup vs baseline: 1.9683x; 1.9683x over previous
//
#include <hip/hip_runtime.h>

#define NATOMS 131072
#define CSTF 1.676543f
#define NREP 16

__device__ __forceinline__ float silu_n(float y) {
    return CSTF * y / (1.0f + __expf(-y));
}

__device__ __forceinline__ float bcast(float v, int lane) {
    return __uint_as_float(__builtin_amdgcn_readlane(__float_as_uint(v), lane));
}

// Per-atom: s2 = silu(silu(x@W0c*.125)@W1c*.125), lane = channel.
// xv holds x[atom][lane]; s1 broadcast via readlane; accumulate coalesced.
#define PROC(xv, a) { \
  float y0=0.f,y1=0.f,y2=0.f,y3=0.f; \
  _Pragma("unroll") \
  for (int m = 0; m < 64; m += 4) { \
    y0 = fmaf(bcast(xv, m+0), w0c[m+0], y0); \
    y1 = fmaf(bcast(xv, m+1), w0c[m+1], y1); \
    y2 = fmaf(bcast(xv, m+2), w0c[m+2], y2); \
    y3 = fmaf(bcast(xv, m+3), w0c[m+3], y3); \
  } \
  const float s1v = silu_n(((y0+y1)+(y2+y3)) * 0.125f); \
  float z0=0.f,z1=0.f,z2=0.f,z3=0.f; \
  _Pragma("unroll") \
  for (int m = 0; m < 64; m += 4) { \
    z0 = fmaf(bcast(s1v, m+0), w1c[m+0], z0); \
    z1 = fmaf(bcast(s1v, m+1), w1c[m+1], z1); \
    z2 = fmaf(bcast(s1v, m+2), w1c[m+2], z2); \
    z3 = fmaf(bcast(s1v, m+3), w1c[m+3], z3); \
  } \
  const float s2v = silu_n(((z0+z1)+(z2+z3)) * 0.125f); \
  const int b = __builtin_amdgcn_readlane(vb, (a)); \
  atomicAdd(&Srep[(b << 6) + lane], s2v); \
}

__global__ __launch_bounds__(256) void phase1(
    const float* __restrict__ x, const int* __restrict__ bidx,
    const float* __restrict__ W0, const float* __restrict__ W1,
    float* __restrict__ S)
{
    const int lane = threadIdx.x & 63;
    const int wv   = blockIdx.x * 4 + (threadIdx.x >> 6);
    const int base = wv * 64;                 // 64 atoms per wave

    // Weight columns W[m, lane] in VGPRs (rows are 256 wide)
    float w0c[64], w1c[64];
#pragma unroll
    for (int m = 0; m < 64; ++m) {
        w0c[m] = W0[m * 256 + lane];
        w1c[m] = W1[m * 256 + lane];
    }
    const int vb = bidx[base + lane];         // lane a holds batch of atom a
    float* Srep = S + ((size_t)(blockIdx.x & (NREP - 1)) << 15);

    const float* xp = x + (size_t)base * 1024 + lane;

    // rolling 4-atom software pipeline
    float c0 = xp[0], c1 = xp[1024], c2 = xp[2048], c3 = xp[3072];
#pragma unroll 1
    for (int g = 0; g < 16; ++g) {
        float n0 = 0.f, n1 = 0.f, n2 = 0.f, n3 = 0.f;
        if (g < 15) {
            const float* q = xp + (size_t)(4 * g + 4) * 1024;
            n0 = q[0]; n1 = q[1024]; n2 = q[2048]; n3 = q[3072];
        }
        const int a0 = 4 * g;
        PROC(c0, a0 + 0);
        PROC(c1, a0 + 1);
        PROC(c2, a0 + 2);
        PROC(c3, a0 + 3);
        c0 = n0; c1 = n1; c2 = n2; c3 = n3;
    }
}

// out[b, t] = 0.125 * sum_o (sum_r S_r[b,o]) * Wout[o, t]
__global__ __launch_bounds__(128) void phase2(
    const float* __restrict__ S, const float* __restrict__ Wout,
    float* __restrict__ out)
{
    __shared__ float sp[64];
    const int b = blockIdx.x, t = threadIdx.x;
    if (t < 64) {
        float s = 0.f;
#pragma unroll
        for (int r = 0; r < NREP; ++r) s += S[((size_t)r << 15) + (b << 6) + t];
        sp[t] = s;
    }
    __syncthreads();
    float acc = 0.f;
#pragma unroll
    for (int o = 0; o < 64; ++o) acc = fmaf(sp[o], Wout[o * 128 + t], acc);
    out[b * 128 + t] = 0.125f * acc;
}

extern "C" void kernel_launch(void* const* d_in, const int* in_sizes, int n_in,
                              void* d_out, int out_size, void* d_ws, size_t ws_size,
                              hipStream_t stream)
{
    const float* x    = (const float*)d_in[0];
    const int*   bidx = (const int*)d_in[1];
    const float* W0   = (const float*)d_in[3];   // W0_0 (64,256)
    const float* W1   = (const float*)d_in[7];   // W1_0 (64,256)
    const float* Wout = (const float*)d_in[11];  // W_out (64,128)
    float* S   = (float*)d_ws;                    // NREP replicas of 512x64
    float* out = (float*)d_out;

    hipMemsetAsync(S, 0, (size_t)NREP * 32768 * sizeof(float), stream);
    hipLaunchKernelGGL(phase1, dim3(512), dim3(256), 0, stream, x, bidx, W0, W1, S);
    hipLaunchKernelGGL(phase2, dim3(512), dim3(128), 0, stream, S, Wout, out);
}

// Round 3
// 46.100 us; speedup vs baseline: 3.6504x; 1.8546x over previous
//
#include <hip/hip_runtime.h>
#include <hip/hip_bf16.h>

#define CSTF 1.676543f
#define NREP 16

typedef __bf16 bf16x8 __attribute__((ext_vector_type(8)));
typedef float  f32x4  __attribute__((ext_vector_type(4)));

__device__ __forceinline__ float silu_n(float y) {
    return CSTF * y / (1.0f + __expf(-y));
}

struct XG { f32x4 a, b, c, d; };

__device__ __forceinline__ XG loadx(const float* p) {
    XG r;
    r.a = *(const f32x4*)(p);
    r.b = *(const f32x4*)(p + 4);
    r.c = *(const f32x4*)(p + 32);
    r.d = *(const f32x4*)(p + 36);
    return r;
}

__device__ __forceinline__ void cvtfrag(const XG& v, bf16x8& a0, bf16x8& a1) {
#pragma unroll
    for (int j = 0; j < 4; ++j) {
        a0[j]     = (__bf16)v.a[j];
        a0[j + 4] = (__bf16)v.b[j];
        a1[j]     = (__bf16)v.c[j];
        a1[j + 4] = (__bf16)v.d[j];
    }
}

// Phase 1: s2 = silu(silu(x@W0*.125)@W1*.125) via bf16 MFMA, atomic-accumulated
// into NREP replicated S[512][64] tables.
__global__ __launch_bounds__(256, 2) void phase1(
    const float* __restrict__ x, const int* __restrict__ bidx,
    const float* __restrict__ W0, const float* __restrict__ W1,
    float* __restrict__ S)
{
    __shared__ __align__(16) __hip_bfloat16 sb[4][16][72];  // per-wave 16x64 (+pad), 144B stride
    const int tid  = threadIdx.x;
    const int lane = tid & 63;
    const int w    = tid >> 6;
    const int c    = lane & 15;   // fragment col / row-within-16
    const int g    = lane >> 4;   // k-group

    // Preload W0/W1 as B-fragments (K=64 in 2 k-steps, N=64 in 4 n-tiles),
    // 1/sqrt(64) norm folded into the bf16 weights.
    bf16x8 wf0[2][4], wf1[2][4];
#pragma unroll
    for (int ks = 0; ks < 2; ++ks)
#pragma unroll
        for (int nt = 0; nt < 4; ++nt) {
            bf16x8 f0, f1;
#pragma unroll
            for (int j = 0; j < 8; ++j) {
                const int k = ks * 32 + g * 8 + j;
                f0[j] = (__bf16)(0.125f * W0[k * 256 + nt * 16 + c]);
                f1[j] = (__bf16)(0.125f * W1[k * 256 + nt * 16 + c]);
            }
            wf0[ks][nt] = f0;
            wf1[ks][nt] = f1;
        }

    float* Srep = S + ((size_t)(blockIdx.x & (NREP - 1)) << 15);
    const int wbase = (blockIdx.x * 4 + w) * 64;      // 64 atoms per wave
    const float* px = x + (size_t)(wbase + c) * 1024 + g * 8;

    XG cur = loadx(px);
#pragma unroll 1
    for (int gi = 0; gi < 4; ++gi) {
        XG nxt = cur;
        if (gi < 3) nxt = loadx(px + (size_t)(gi + 1) * 16 * 1024);
        const int gbase = wbase + gi * 16;

        bf16x8 a0, a1;
        cvtfrag(cur, a0, a1);

        // layer 1: 16x64 = (16 atoms x 64ch) @ W0
        const f32x4 zf = {0.f, 0.f, 0.f, 0.f};
#pragma unroll
        for (int nt = 0; nt < 4; ++nt) {
            f32x4 acc = __builtin_amdgcn_mfma_f32_16x16x32_bf16(a0, wf0[0][nt], zf, 0, 0, 0);
            acc = __builtin_amdgcn_mfma_f32_16x16x32_bf16(a1, wf0[1][nt], acc, 0, 0, 0);
            // C layout: row = 4g + r, col = nt*16 + c  -> LDS transpose
#pragma unroll
            for (int r = 0; r < 4; ++r)
                sb[w][4 * g + r][nt * 16 + c] = __float2bfloat16(silu_n(acc[r]));
        }

        // re-read as A-fragments: lane holds row c, k = g*8+j (+32)
        const bf16x8 sa0 = *(const bf16x8*)&sb[w][c][g * 8];
        const bf16x8 sa1 = *(const bf16x8*)&sb[w][c][g * 8 + 32];

        int br[4];
#pragma unroll
        for (int r = 0; r < 4; ++r) br[r] = bidx[gbase + 4 * g + r];

        // layer 2 + atomic accumulate
#pragma unroll
        for (int nt = 0; nt < 4; ++nt) {
            f32x4 z = __builtin_amdgcn_mfma_f32_16x16x32_bf16(sa0, wf1[0][nt], zf, 0, 0, 0);
            z = __builtin_amdgcn_mfma_f32_16x16x32_bf16(sa1, wf1[1][nt], z, 0, 0, 0);
#pragma unroll
            for (int r = 0; r < 4; ++r)
                atomicAdd(&Srep[(br[r] << 6) + nt * 16 + c], silu_n(z[r]));
        }
        cur = nxt;
    }
}

// out[b, t] = 0.125 * sum_o (sum_r S_r[b,o]) * Wout[o, t]
__global__ __launch_bounds__(128) void phase2(
    const float* __restrict__ S, const float* __restrict__ Wout,
    float* __restrict__ out)
{
    __shared__ float sp[64];
    const int b = blockIdx.x, t = threadIdx.x;
    if (t < 64) {
        float s = 0.f;
#pragma unroll
        for (int r = 0; r < NREP; ++r) s += S[((size_t)r << 15) + (b << 6) + t];
        sp[t] = s;
    }
    __syncthreads();
    float acc = 0.f;
#pragma unroll
    for (int o = 0; o < 64; ++o) acc = fmaf(sp[o], Wout[o * 128 + t], acc);
    out[b * 128 + t] = 0.125f * acc;
}

extern "C" void kernel_launch(void* const* d_in, const int* in_sizes, int n_in,
                              void* d_out, int out_size, void* d_ws, size_t ws_size,
                              hipStream_t stream)
{
    const float* x    = (const float*)d_in[0];
    const int*   bidx = (const int*)d_in[1];
    const float* W0   = (const float*)d_in[3];   // W0_0 (64,256)
    const float* W1   = (const float*)d_in[7];   // W1_0 (64,256)
    const float* Wout = (const float*)d_in[11];  // W_out (64,128)
    float* S   = (float*)d_ws;                    // NREP replicas of 512x64
    float* out = (float*)d_out;

    hipMemsetAsync(S, 0, (size_t)NREP * 32768 * sizeof(float), stream);
    hipLaunchKernelGGL(phase1, dim3(512), dim3(256), 0, stream, x, bidx, W0, W1, S);
    hipLaunchKernelGGL(phase2, dim3(512), dim3(128), 0, stream, S, Wout, out);
}